// Round 2
// baseline (528.906 us; speedup 1.0000x reference)
//
#include <hip/hip_runtime.h>
#include <cstdint>
#include <cstddef>

// ---------------------------------------------------------------------------
// HarmonicTransformerLayer  B=2 S=2048 D=1024 H=16 HD=64 F=4096
// Round 1: resubmit round-0 baseline (round 1 was a GPU-acquisition timeout;
// no measurement exists yet for this kernel).
//   - all heavy GEMMs: bf16 MFMA 16x16x32, 128-tile, 2-barrier loop (m90/m92)
//   - fused QKV GEMM (N=3072), flash attention w/ harmonic score mod,
//     fused bias+spectral epilogue, residual+harmonic-LN kernel
// ---------------------------------------------------------------------------

typedef float  f32x4  __attribute__((ext_vector_type(4)));
typedef __bf16 bf16x8 __attribute__((ext_vector_type(8)));
typedef unsigned short u16x8 __attribute__((ext_vector_type(8)));
typedef unsigned short u16x4 __attribute__((ext_vector_type(4)));

#define MFMA_BF16(a, b, c) __builtin_amdgcn_mfma_f32_16x16x32_bf16((a), (b), (c), 0, 0, 0)

static __device__ __forceinline__ unsigned short f32_to_bf16(float f) {
  unsigned int u = __float_as_uint(f);
  u += 0x7fffu + ((u >> 16) & 1u);          // RNE
  return (unsigned short)(u >> 16);
}
static __device__ __forceinline__ float bf16_to_f32(unsigned short h) {
  return __uint_as_float(((unsigned int)h) << 16);
}
static __device__ __forceinline__ bf16x8 lds_frag(const unsigned short* base, int byte) {
  return __builtin_bit_cast(bf16x8, *(const u16x8*)((const char*)base + byte));
}
static __device__ __forceinline__ float spectral_act(float x) {
  const float c = 0.7978845608028654f;      // sqrt(2/pi)
  float g = 0.5f * x * (1.0f + tanhf(c * (x + 0.044715f * x * x * x)));
  return g + 0.5f * __sinf(x);              // ALPHA=0.5, BETA=1.0
}

// ---------------------------------------------------------------------------
// fp32 -> bf16 vector convert
// ---------------------------------------------------------------------------
__global__ __launch_bounds__(256) void cvt_f32_bf16(const float* __restrict__ in,
                                                    unsigned short* __restrict__ out, int n) {
  int i = (blockIdx.x * 256 + threadIdx.x) * 4;
  if (i < n) {
    float4 v = *(const float4*)(in + i);
    u16x4 o;
    o[0] = f32_to_bf16(v.x); o[1] = f32_to_bf16(v.y);
    o[2] = f32_to_bf16(v.z); o[3] = f32_to_bf16(v.w);
    *(u16x4*)(out + i) = o;
  }
}

// ---------------------------------------------------------------------------
// W [K][N] fp32  ->  Wt [N][K] bf16   (32x32 LDS tile transpose)
// ---------------------------------------------------------------------------
__global__ __launch_bounds__(256) void transpose_f32_bf16(const float* __restrict__ W,
                                                          unsigned short* __restrict__ Wt,
                                                          int K, int N) {
  __shared__ float tile[32][33];
  int tx = threadIdx.x & 31, ty = threadIdx.x >> 5;   // 32 x 8
  int k0 = blockIdx.y * 32, n0 = blockIdx.x * 32;
#pragma unroll
  for (int i = 0; i < 4; i++)
    tile[ty + i * 8][tx] = W[(size_t)(k0 + ty + i * 8) * N + n0 + tx];
  __syncthreads();
#pragma unroll
  for (int i = 0; i < 4; i++)
    Wt[(size_t)(n0 + ty + i * 8) * K + k0 + tx] = f32_to_bf16(tile[tx][ty + i * 8]);
}

// ---------------------------------------------------------------------------
// GEMM: C[M,N] = A[M,K](bf16) @ Bt[N,K]^T(bf16) + bias
// EPI 0: bf16 out, 1: fp32 out, 2: spectral(act) -> bf16 out
// 4 waves, wave tile (BM/2)x(BN/2), mfma 16x16x32, XOR-swizzled LDS.
// ---------------------------------------------------------------------------
template <int BM, int BN, int EPI>
__global__ __launch_bounds__(256) void gemm_bt(const unsigned short* __restrict__ A,
                                               const unsigned short* __restrict__ Bt,
                                               const float* __restrict__ bias,
                                               unsigned short* __restrict__ Cb,
                                               float* __restrict__ Cf,
                                               int M, int N, int K) {
  constexpr int MI = BM / 32;   // m-frags per wave
  constexpr int NI = BN / 32;   // n-frags per wave
  __shared__ unsigned short As[BM * 32];
  __shared__ unsigned short Bs[BN * 32];
  const int t = threadIdx.x;
  const int lane = t & 63, w = t >> 6;
  const int wr = w >> 1, wc = w & 1;
  const int g = lane >> 4, cc = lane & 15;
  const int row0 = blockIdx.y * BM, col0 = blockIdx.x * BN;

  f32x4 acc[MI][NI];
#pragma unroll
  for (int mi = 0; mi < MI; mi++)
#pragma unroll
    for (int ni = 0; ni < NI; ni++) acc[mi][ni] = (f32x4){0.f, 0.f, 0.f, 0.f};

  const int nk = K >> 5;
  const int sr = t >> 2, sc = (t & 3) * 8;     // staging: row, col8

  for (int kt = 0; kt < nk; ++kt) {
    __syncthreads();
#pragma unroll
    for (int i = 0; i < BM / 64; ++i) {
      int r = sr + i * 64;
      u16x8 v = *(const u16x8*)(A + (size_t)(row0 + r) * K + (kt << 5) + sc);
      *(u16x8*)((char*)As + ((r * 64 + sc * 2) ^ ((r & 7) << 4))) = v;
    }
#pragma unroll
    for (int i = 0; i < BN / 64; ++i) {
      int r = sr + i * 64;
      u16x8 v = *(const u16x8*)(Bt + (size_t)(col0 + r) * K + (kt << 5) + sc);
      *(u16x8*)((char*)Bs + ((r * 64 + sc * 2) ^ ((r & 7) << 4))) = v;
    }
    __syncthreads();

    bf16x8 af[MI], bg[NI];
#pragma unroll
    for (int mi = 0; mi < MI; mi++) {
      int r = wr * (BM / 2) + mi * 16 + cc;
      af[mi] = lds_frag(As, (r * 64 + g * 16) ^ ((r & 7) << 4));
    }
#pragma unroll
    for (int ni = 0; ni < NI; ni++) {
      int r = wc * (BN / 2) + ni * 16 + cc;
      bg[ni] = lds_frag(Bs, (r * 64 + g * 16) ^ ((r & 7) << 4));
    }
#pragma unroll
    for (int mi = 0; mi < MI; mi++)
#pragma unroll
      for (int ni = 0; ni < NI; ni++)
        acc[mi][ni] = MFMA_BF16(af[mi], bg[ni], acc[mi][ni]);
  }

#pragma unroll
  for (int mi = 0; mi < MI; mi++) {
#pragma unroll
    for (int ni = 0; ni < NI; ni++) {
      int col = col0 + wc * (BN / 2) + ni * 16 + cc;
      float bv = bias[col];
#pragma unroll
      for (int r4 = 0; r4 < 4; r4++) {
        int row = row0 + wr * (BM / 2) + mi * 16 + g * 4 + r4;
        float val = acc[mi][ni][r4] + bv;
        if (EPI == 2) val = spectral_act(val);
        if (EPI == 0 || EPI == 2) Cb[(size_t)row * N + col] = f32_to_bf16(val);
        else                      Cf[(size_t)row * N + col] = val;
      }
    }
  }
}

// ---------------------------------------------------------------------------
// Flash attention with harmonic score modification.
// grid (S/64, B*H); 4 waves, each wave owns 16 q-rows. 64-key tiles.
// scores s = (q.k)/8 ; s' = s + res*sin(s+ph) ; online softmax ; o = P@V
// ---------------------------------------------------------------------------
__global__ __launch_bounds__(256) void attn_fused(const unsigned short* __restrict__ Qb,
                                                  const unsigned short* __restrict__ Kb,
                                                  const unsigned short* __restrict__ Vb,
                                                  int ld,
                                                  const float* __restrict__ resonance,
                                                  const float* __restrict__ phase,
                                                  unsigned short* __restrict__ O, int ldo) {
  constexpr int S = 2048;
  __shared__ unsigned short Ks[64 * 64];     // [key][hd], XOR swizzled
  __shared__ unsigned short Vs[64 * 64];     // [hd][key] (transposed), XOR swizzled
  __shared__ unsigned short Ps[4][16 * 64];  // per-wave P staging

  const int t = threadIdx.x, lane = t & 63, w = t >> 6;
  const int g = lane >> 4, cc = lane & 15;
  const int bh = blockIdx.y, b = bh >> 4, h = bh & 15;
  const int q0 = blockIdx.x * 64 + w * 16;
  const float res = resonance[h], ph = phase[h];

  const unsigned short* Qh = Qb + (size_t)b * S * ld + h * 64;
  const unsigned short* Kh = Kb + (size_t)b * S * ld + h * 64;
  const unsigned short* Vh = Vb + (size_t)b * S * ld + h * 64;

  // Q fragments (A operand: m = lane&15, k = 8*(lane>>4)+j)
  bf16x8 qa0, qa1;
  {
    const unsigned short* qp = Qh + (size_t)(q0 + cc) * ld + g * 8;
    qa0 = __builtin_bit_cast(bf16x8, *(const u16x8*)qp);
    qa1 = __builtin_bit_cast(bf16x8, *(const u16x8*)(qp + 32));
  }

  f32x4 oacc[4];
#pragma unroll
  for (int i = 0; i < 4; i++) oacc[i] = (f32x4){0.f, 0.f, 0.f, 0.f};
  float Mx[4] = {-1e30f, -1e30f, -1e30f, -1e30f};
  float Lx[4] = {0.f, 0.f, 0.f, 0.f};
  char* PsW = (char*)&Ps[w][0];

  for (int kt = 0; kt < S / 64; ++kt) {
    __syncthreads();
    {  // stage K tile [64 keys][64 hd]
      int r = t >> 3, c8 = (t & 7) * 8;
      const unsigned short* kp = Kh + (size_t)(kt * 64) * ld;
#pragma unroll
      for (int hh = 0; hh < 2; ++hh) {
        int row = r + hh * 32;
        u16x8 v = *(const u16x8*)(kp + (size_t)row * ld + c8);
        *(u16x8*)((char*)Ks + ((row * 128 + c8 * 2) ^ ((row & 7) << 4))) = v;
      }
      // stage V transposed: Vs[hd][key]
      int key = t & 63, hb0 = (t >> 6) * 16;
      const unsigned short* vp = Vh + (size_t)(kt * 64 + key) * ld + hb0;
      u16x8 v0 = *(const u16x8*)vp;
      u16x8 v1 = *(const u16x8*)(vp + 8);
#pragma unroll
      for (int j = 0; j < 8; j++) {
        int hd0 = hb0 + j;
        *(unsigned short*)((char*)Vs + ((hd0 * 128 + key * 2) ^ ((hd0 & 7) << 4))) = v0[j];
        int hd1 = hb0 + 8 + j;
        *(unsigned short*)((char*)Vs + ((hd1 * 128 + key * 2) ^ ((hd1 & 7) << 4))) = v1[j];
      }
    }
    __syncthreads();

    // QK^T : 16 q-rows x 64 keys
    f32x4 sacc[4];
#pragma unroll
    for (int nb = 0; nb < 4; nb++) sacc[nb] = (f32x4){0.f, 0.f, 0.f, 0.f};
#pragma unroll
    for (int nb = 0; nb < 4; nb++) {
      int key = nb * 16 + cc;
      int rb = key * 128, xr = (key & 7) << 4;
      bf16x8 k0 = lds_frag(Ks, (rb + g * 16) ^ xr);
      bf16x8 k1 = lds_frag(Ks, (rb + 64 + g * 16) ^ xr);
      sacc[nb] = MFMA_BF16(qa0, k0, sacc[nb]);
      sacc[nb] = MFMA_BF16(qa1, k1, sacc[nb]);
    }

    // harmonic modification + row max
    float sm[4] = {-1e30f, -1e30f, -1e30f, -1e30f};
#pragma unroll
    for (int nb = 0; nb < 4; nb++)
#pragma unroll
      for (int r4 = 0; r4 < 4; r4++) {
        float sv = sacc[nb][r4] * 0.125f;          // / sqrt(64)
        sv += res * __sinf(sv + ph);
        sacc[nb][r4] = sv;
        sm[r4] = fmaxf(sm[r4], sv);
      }
#pragma unroll
    for (int d = 1; d < 16; d <<= 1)
#pragma unroll
      for (int r4 = 0; r4 < 4; r4++) sm[r4] = fmaxf(sm[r4], __shfl_xor(sm[r4], d, 16));

    float alpha[4], psum[4] = {0.f, 0.f, 0.f, 0.f};
#pragma unroll
    for (int r4 = 0; r4 < 4; r4++) {
      float nm = fmaxf(Mx[r4], sm[r4]);
      alpha[r4] = __expf(Mx[r4] - nm);
      Mx[r4] = nm;
    }
    // P = exp(s - M) -> bf16 into LDS (A-operand layout via XOR-swizzled stage)
#pragma unroll
    for (int nb = 0; nb < 4; nb++)
#pragma unroll
      for (int r4 = 0; r4 < 4; r4++) {
        float p = __expf(sacc[nb][r4] - Mx[r4]);
        unsigned short pu = f32_to_bf16(p);
        psum[r4] += bf16_to_f32(pu);
        int prow = g * 4 + r4, pcol = nb * 16 + cc;
        *(unsigned short*)(PsW + ((prow * 128 + pcol * 2) ^ ((prow & 7) << 4))) = pu;
      }
#pragma unroll
    for (int d = 1; d < 16; d <<= 1)
#pragma unroll
      for (int r4 = 0; r4 < 4; r4++) psum[r4] += __shfl_xor(psum[r4], d, 16);
#pragma unroll
    for (int r4 = 0; r4 < 4; r4++) Lx[r4] = Lx[r4] * alpha[r4] + psum[r4];
#pragma unroll
    for (int nb2 = 0; nb2 < 4; nb2++)
#pragma unroll
      for (int r4 = 0; r4 < 4; r4++) oacc[nb2][r4] *= alpha[r4];

    // PV: o += P(16x64) @ V(64x64)
    bf16x8 pa0, pa1;
    {
      int xr = (cc & 7) << 4;
      pa0 = lds_frag((const unsigned short*)PsW, (cc * 128 + g * 16) ^ xr);
      pa1 = lds_frag((const unsigned short*)PsW, (cc * 128 + 64 + g * 16) ^ xr);
    }
#pragma unroll
    for (int nb2 = 0; nb2 < 4; nb2++) {
      int hd = nb2 * 16 + cc;
      int rb = hd * 128, xr = (hd & 7) << 4;
      bf16x8 v0 = lds_frag(Vs, (rb + g * 16) ^ xr);
      bf16x8 v1 = lds_frag(Vs, (rb + 64 + g * 16) ^ xr);
      oacc[nb2] = MFMA_BF16(pa0, v0, oacc[nb2]);
      oacc[nb2] = MFMA_BF16(pa1, v1, oacc[nb2]);
    }
  }

  // epilogue: normalize, write bf16 [B*S][ldo]
#pragma unroll
  for (int nb2 = 0; nb2 < 4; nb2++)
#pragma unroll
    for (int r4 = 0; r4 < 4; r4++) {
      float ov = oacc[nb2][r4] / Lx[r4];
      O[(size_t)(b * S + q0 + g * 4 + r4) * ldo + h * 64 + nb2 * 16 + cc] = f32_to_bf16(ov);
    }
}

// ---------------------------------------------------------------------------
// y = harmonic_ln(xin + radd): mean/std(ddof=1), std += stab*sin(pi*std)
// one block per row (D=1024). yf fp32 (required), yb bf16 (optional)
// ---------------------------------------------------------------------------
__global__ __launch_bounds__(256) void resid_harmonic_ln(const float* __restrict__ xin,
                                                         const float* __restrict__ radd,
                                                         const float* __restrict__ gamma,
                                                         const float* __restrict__ beta,
                                                         const float* __restrict__ stab,
                                                         float* __restrict__ yf,
                                                         unsigned short* __restrict__ yb) {
  const int row = blockIdx.x, t = threadIdx.x;
  const float* xr = xin + (size_t)row * 1024;
  const float* rr = radd + (size_t)row * 1024;
  float v[4], s = 0.f, ss = 0.f;
#pragma unroll
  for (int j = 0; j < 4; j++) {
    int idx = t + j * 256;
    v[j] = xr[idx] + rr[idx];
    s += v[j]; ss += v[j] * v[j];
  }
#pragma unroll
  for (int d = 1; d < 64; d <<= 1) { s += __shfl_xor(s, d); ss += __shfl_xor(ss, d); }
  __shared__ float sb[8];
  int lane = t & 63, wid = t >> 6;
  if (lane == 0) { sb[wid] = s; sb[4 + wid] = ss; }
  __syncthreads();
  s = sb[0] + sb[1] + sb[2] + sb[3];
  ss = sb[4] + sb[5] + sb[6] + sb[7];
  float mean = s * (1.f / 1024.f);
  float var = fmaxf((ss - 1024.f * mean * mean) * (1.f / 1023.f), 0.f);  // ddof=1
  float sd = sqrtf(var);
  sd += stab[0] * sinf(sd * 3.14159265358979323846f);
  float inv = 1.f / (sd + 1e-6f);
#pragma unroll
  for (int j = 0; j < 4; j++) {
    int idx = t + j * 256;
    float y = gamma[idx] * ((v[j] - mean) * inv) + beta[idx];
    yf[(size_t)row * 1024 + idx] = y;
    if (yb) yb[(size_t)row * 1024 + idx] = f32_to_bf16(y);
  }
}

// ---------------------------------------------------------------------------
extern "C" void kernel_launch(void* const* d_in, const int* in_sizes, int n_in,
                              void* d_out, int out_size, void* d_ws, size_t ws_size,
                              hipStream_t stream) {
  const float* x    = (const float*)d_in[0];
  const float* Wq   = (const float*)d_in[1];
  const float* bq   = (const float*)d_in[2];
  const float* Wk   = (const float*)d_in[3];
  const float* bk   = (const float*)d_in[4];
  const float* Wv   = (const float*)d_in[5];
  const float* bv   = (const float*)d_in[6];
  const float* Wo   = (const float*)d_in[7];
  const float* bo   = (const float*)d_in[8];
  const float* reso = (const float*)d_in[9];
  const float* phas = (const float*)d_in[10];
  const float* g1   = (const float*)d_in[11];
  const float* b1   = (const float*)d_in[12];
  const float* s1   = (const float*)d_in[13];
  const float* W1   = (const float*)d_in[14];
  const float* bf1  = (const float*)d_in[15];
  const float* W2   = (const float*)d_in[16];
  const float* bf2  = (const float*)d_in[17];
  const float* g2   = (const float*)d_in[18];
  const float* b2   = (const float*)d_in[19];
  const float* s2   = (const float*)d_in[20];

  const int BS = 4096;  // B*S

  // workspace layout (bytes); hb aliases qkv+xb (their lifetimes end first)
  char* ws = (char*)d_ws;
  const size_t OFF_QKV  = 0;                 // qkv bf16 [4096][3072]   25165824
  const size_t OFF_XB   = 25165824;          // xb bf16  [4096][1024]    8388608  (later: ao)
  const size_t OFF_WQKV = 33554432;          // Wqkv^T bf16 [3072][1024] 6291456
  const size_t OFF_WOT  = 39845888;          // Wo^T bf16 [1024][1024]   2097152
  const size_t OFF_W1T  = 41943040;          // W1^T bf16 [4096][1024]   8388608
  const size_t OFF_W2T  = 50331648;          // W2^T bf16 [1024][4096]   8388608
  const size_t OFF_BQKV = 58720256;          // bqkv f32 [3072]            12288
  const size_t OFF_T0   = 58736640;          // t0 f32 [4096][1024]     16777216
  const size_t OFF_X1   = 75513856;          // x1 f32 [4096][1024]     16777216
  const size_t OFF_X1B  = 92291072;          // x1b bf16 [4096][1024]    8388608
  // hb bf16 [4096][4096] = 33554432 @ offset 0 (over dead qkv+xb)

  unsigned short* qkv   = (unsigned short*)(ws + OFF_QKV);
  unsigned short* xb    = (unsigned short*)(ws + OFF_XB);
  unsigned short* ao    = (unsigned short*)(ws + OFF_XB);
  unsigned short* Wqkvt = (unsigned short*)(ws + OFF_WQKV);
  unsigned short* Wot   = (unsigned short*)(ws + OFF_WOT);
  unsigned short* W1t   = (unsigned short*)(ws + OFF_W1T);
  unsigned short* W2t   = (unsigned short*)(ws + OFF_W2T);
  float*          bqkv  = (float*)(ws + OFF_BQKV);
  float*          t0    = (float*)(ws + OFF_T0);
  float*          x1    = (float*)(ws + OFF_X1);
  unsigned short* x1b   = (unsigned short*)(ws + OFF_X1B);
  unsigned short* hb    = (unsigned short*)(ws + OFF_QKV);
  float*          out   = (float*)d_out;

  // 1. x -> bf16
  cvt_f32_bf16<<<4096, 256, 0, stream>>>(x, xb, BS * 1024);

  // 2. weight transposes (fp32 [K][N] -> bf16 [N][K])
  transpose_f32_bf16<<<dim3(32, 32), 256, 0, stream>>>(Wq, Wqkvt, 1024, 1024);
  transpose_f32_bf16<<<dim3(32, 32), 256, 0, stream>>>(Wk, Wqkvt + (size_t)1024 * 1024, 1024, 1024);
  transpose_f32_bf16<<<dim3(32, 32), 256, 0, stream>>>(Wv, Wqkvt + (size_t)2048 * 1024, 1024, 1024);
  transpose_f32_bf16<<<dim3(32, 32), 256, 0, stream>>>(Wo, Wot, 1024, 1024);
  transpose_f32_bf16<<<dim3(128, 32), 256, 0, stream>>>(W1, W1t, 1024, 4096);
  transpose_f32_bf16<<<dim3(32, 128), 256, 0, stream>>>(W2, W2t, 4096, 1024);

  // 3. pack qkv bias
  hipMemcpyAsync((void*)bqkv,          (const void*)bq, 1024 * 4, hipMemcpyDeviceToDevice, stream);
  hipMemcpyAsync((void*)(bqkv + 1024), (const void*)bk, 1024 * 4, hipMemcpyDeviceToDevice, stream);
  hipMemcpyAsync((void*)(bqkv + 2048), (const void*)bv, 1024 * 4, hipMemcpyDeviceToDevice, stream);

  // 4. fused QKV projection: [4096,1024] @ [1024,3072] -> bf16 qkv
  gemm_bt<128, 128, 0><<<dim3(24, 32), 256, 0, stream>>>(xb, Wqkvt, bqkv, qkv, nullptr,
                                                         4096, 3072, 1024);

  // 5. attention (reads q/k/v slices of packed qkv, ld=3072) -> ao bf16
  attn_fused<<<dim3(32, 32), 256, 0, stream>>>(qkv, qkv + 1024, qkv + 2048, 3072,
                                               reso, phas, ao, 1024);

  // 6. output projection -> t0 fp32
  gemm_bt<128, 64, 1><<<dim3(16, 32), 256, 0, stream>>>(ao, Wot, bo, nullptr, t0,
                                                        4096, 1024, 1024);

  // 7. x1 = harmonic_ln(x + attn_out)
  resid_harmonic_ln<<<4096, 256, 0, stream>>>(x, t0, g1, b1, s1, x1, x1b);

  // 8. FFN up + spectral activation -> hb bf16
  gemm_bt<128, 128, 2><<<dim3(32, 32), 256, 0, stream>>>(x1b, W1t, bf1, hb, nullptr,
                                                         4096, 4096, 1024);

  // 9. FFN down -> t0 fp32
  gemm_bt<128, 64, 1><<<dim3(16, 32), 256, 0, stream>>>(hb, W2t, bf2, nullptr, t0,
                                                        4096, 1024, 4096);

  // 10. out = harmonic_ln(x1 + ff)
  resid_harmonic_ln<<<4096, 256, 0, stream>>>(x1, t0, g2, b2, s2, out, nullptr);
}

// Round 4
// 524.735 us; speedup vs baseline: 1.0079x; 1.0079x over previous
//
#include <hip/hip_runtime.h>
#include <cstdint>
#include <cstddef>

// ---------------------------------------------------------------------------
// HarmonicTransformerLayer  B=2 S=2048 D=1024 H=16 HD=64 F=4096
// Round 4 (= round-3 kernel, resubmitted after acquisition timeout):
//   - GEMMs: global_load_lds width=16 staging (m97), linear LDS + row-local
//     chunk XOR pre-swizzled on the global source
//   - attn: native bf16 cvt, psum via ones-MFMA (no shuffle reduce),
//     V staged row-major [4][64][16] + ds_read_b64_tr_b16 PV fragments
// ---------------------------------------------------------------------------

typedef float  f32x4  __attribute__((ext_vector_type(4)));
typedef __bf16 bf16x8 __attribute__((ext_vector_type(8)));
typedef unsigned short u16x8 __attribute__((ext_vector_type(8)));
typedef unsigned short u16x4 __attribute__((ext_vector_type(4)));
typedef unsigned int   u32x2 __attribute__((ext_vector_type(2)));
typedef unsigned int   u32x4 __attribute__((ext_vector_type(4)));

#define MFMA_BF16(a, b, c) __builtin_amdgcn_mfma_f32_16x16x32_bf16((a), (b), (c), 0, 0, 0)

static __device__ __forceinline__ unsigned short f32_to_bf16(float f) {
  return __builtin_bit_cast(unsigned short, (__bf16)f);   // HW RNE cvt on gfx950
}
static __device__ __forceinline__ bf16x8 lds_frag(const unsigned short* base, int byte) {
  return __builtin_bit_cast(bf16x8, *(const u16x8*)((const char*)base + byte));
}
static __device__ __forceinline__ float spectral_act(float x) {
  const float c = 0.7978845608028654f;      // sqrt(2/pi)
  float g = 0.5f * x * (1.0f + tanhf(c * (x + 0.044715f * x * x * x)));
  return g + 0.5f * __sinf(x);              // ALPHA=0.5, BETA=1.0
}
static __device__ __forceinline__ void gload_lds16(const void* g, void* lds) {
  __builtin_amdgcn_global_load_lds((const __attribute__((address_space(1))) unsigned int*)g,
                                   (__attribute__((address_space(3))) unsigned int*)lds,
                                   16, 0, 0);
}
// ds_read_b64_tr_b16: per 16-lane group crossbar; lane i elem j =
// elem(i&3) of chunk supplied by lane 4j+(i>>2). offset folded into addr.
static __device__ __forceinline__ u32x2 tr_read(unsigned addr) {
  u32x2 r;
  asm volatile("ds_read_b64_tr_b16 %0, %1" : "=v"(r) : "v"(addr));
  return r;
}

// ---------------------------------------------------------------------------
// fp32 -> bf16 vector convert
// ---------------------------------------------------------------------------
__global__ __launch_bounds__(256) void cvt_f32_bf16(const float* __restrict__ in,
                                                    unsigned short* __restrict__ out, int n) {
  int i = (blockIdx.x * 256 + threadIdx.x) * 4;
  if (i < n) {
    float4 v = *(const float4*)(in + i);
    u16x4 o;
    o[0] = f32_to_bf16(v.x); o[1] = f32_to_bf16(v.y);
    o[2] = f32_to_bf16(v.z); o[3] = f32_to_bf16(v.w);
    *(u16x4*)(out + i) = o;
  }
}

// ---------------------------------------------------------------------------
// W [K][N] fp32  ->  Wt [N][K] bf16   (32x32 LDS tile transpose)
// ---------------------------------------------------------------------------
__global__ __launch_bounds__(256) void transpose_f32_bf16(const float* __restrict__ W,
                                                          unsigned short* __restrict__ Wt,
                                                          int K, int N) {
  __shared__ float tile[32][33];
  int tx = threadIdx.x & 31, ty = threadIdx.x >> 5;   // 32 x 8
  int k0 = blockIdx.y * 32, n0 = blockIdx.x * 32;
#pragma unroll
  for (int i = 0; i < 4; i++)
    tile[ty + i * 8][tx] = W[(size_t)(k0 + ty + i * 8) * N + n0 + tx];
  __syncthreads();
#pragma unroll
  for (int i = 0; i < 4; i++)
    Wt[(size_t)(n0 + ty + i * 8) * K + k0 + tx] = f32_to_bf16(tile[tx][ty + i * 8]);
}

// ---------------------------------------------------------------------------
// GEMM: C[M,N] = A[M,K](bf16) @ Bt[N,K]^T(bf16) + bias
// EPI 0: bf16 out, 1: fp32 out, 2: spectral(act) -> bf16 out
// 4 waves, wave tile (BM/2)x(BN/2), mfma 16x16x32.
// Staging: global_load_lds dwordx4, linear LDS [rows][32] (64B rows),
// global source pre-swizzled chunk^=(r&3); reads use chunk = g^(r&3).
// ---------------------------------------------------------------------------
template <int BM, int BN, int EPI>
__global__ __launch_bounds__(256) void gemm_bt(const unsigned short* __restrict__ A,
                                               const unsigned short* __restrict__ Bt,
                                               const float* __restrict__ bias,
                                               unsigned short* __restrict__ Cb,
                                               float* __restrict__ Cf,
                                               int M, int N, int K) {
  constexpr int MI = BM / 32;   // m-frags per wave
  constexpr int NI = BN / 32;   // n-frags per wave
  __shared__ unsigned short As[BM * 32];
  __shared__ unsigned short Bs[BN * 32];
  const int t = threadIdx.x;
  const int lane = t & 63, w = t >> 6;
  const int wr = w >> 1, wc = w & 1;
  const int g = lane >> 4, cc = lane & 15;
  const int row0 = blockIdx.y * BM, col0 = blockIdx.x * BN;

  f32x4 acc[MI][NI];
#pragma unroll
  for (int mi = 0; mi < MI; mi++)
#pragma unroll
    for (int ni = 0; ni < NI; ni++) acc[mi][ni] = (f32x4){0.f, 0.f, 0.f, 0.f};

  const int nk = K >> 5;
  // staging: wave covers 16 rows/round; lane -> row lane>>2, chunk pre-swizzled
  const int srow = lane >> 2;
  const int schunk = (lane & 3) ^ ((lane >> 2) & 3);

  for (int kt = 0; kt < nk; ++kt) {
#pragma unroll
    for (int i = 0; i < BM / 64; ++i) {
      int r = i * 64 + w * 16 + srow;
      gload_lds16(A + (size_t)(row0 + r) * K + (kt << 5) + schunk * 8,
                  As + (i * 64 + w * 16) * 32);
    }
#pragma unroll
    for (int i = 0; i < BN / 64; ++i) {
      int r = i * 64 + w * 16 + srow;
      gload_lds16(Bt + (size_t)(col0 + r) * K + (kt << 5) + schunk * 8,
                  Bs + (i * 64 + w * 16) * 32);
    }
    __syncthreads();   // drains vmcnt (compiler) -> staged data visible

    bf16x8 af[MI], bg[NI];
#pragma unroll
    for (int mi = 0; mi < MI; mi++) {
      int r = wr * (BM / 2) + mi * 16 + cc;
      af[mi] = lds_frag(As, r * 64 + ((g ^ (cc & 3)) << 4));
    }
#pragma unroll
    for (int ni = 0; ni < NI; ni++) {
      int r = wc * (BN / 2) + ni * 16 + cc;
      bg[ni] = lds_frag(Bs, r * 64 + ((g ^ (cc & 3)) << 4));
    }
#pragma unroll
    for (int mi = 0; mi < MI; mi++)
#pragma unroll
      for (int ni = 0; ni < NI; ni++)
        acc[mi][ni] = MFMA_BF16(af[mi], bg[ni], acc[mi][ni]);
    __syncthreads();   // all reads done before next stage overwrites
  }

#pragma unroll
  for (int mi = 0; mi < MI; mi++) {
#pragma unroll
    for (int ni = 0; ni < NI; ni++) {
      int col = col0 + wc * (BN / 2) + ni * 16 + cc;
      float bv = bias[col];
#pragma unroll
      for (int r4 = 0; r4 < 4; r4++) {
        int row = row0 + wr * (BM / 2) + mi * 16 + g * 4 + r4;
        float val = acc[mi][ni][r4] + bv;
        if (EPI == 2) val = spectral_act(val);
        if (EPI == 0 || EPI == 2) Cb[(size_t)row * N + col] = f32_to_bf16(val);
        else                      Cf[(size_t)row * N + col] = val;
      }
    }
  }
}

// ---------------------------------------------------------------------------
// Flash attention with harmonic score modification.
// grid (S/64, B*H); 4 waves, each wave owns 16 q-rows. 64-key tiles.
// scores s = (q.k)/8 ; s' = s + res*sin(s+ph) ; online softmax ; o = P@V
// V in LDS as 4 tiles [64 keys][16 hd] (32B rows, 16B-half swizzle by
// (key>>3)&1); PV B-fragments via ds_read_b64_tr_b16.
// ---------------------------------------------------------------------------
__global__ __launch_bounds__(256) void attn_fused(const unsigned short* __restrict__ Qb,
                                                  const unsigned short* __restrict__ Kb,
                                                  const unsigned short* __restrict__ Vb,
                                                  int ld,
                                                  const float* __restrict__ resonance,
                                                  const float* __restrict__ phase,
                                                  unsigned short* __restrict__ O, int ldo) {
  constexpr int S = 2048;
  __shared__ unsigned short Ks[64 * 64];     // [key][hd], XOR swizzled
  __shared__ unsigned short Vs[4][64 * 16];  // [hd_blk][key][hd%16], half-swizzled
  __shared__ unsigned short Ps[4][16 * 64];  // per-wave P staging

  const int t = threadIdx.x, lane = t & 63, w = t >> 6;
  const int g = lane >> 4, cc = lane & 15;
  const int bh = blockIdx.y, b = bh >> 4, h = bh & 15;
  const int q0 = blockIdx.x * 64 + w * 16;
  const float res = resonance[h], ph = phase[h];

  const unsigned short* Qh = Qb + (size_t)b * S * ld + h * 64;
  const unsigned short* Kh = Kb + (size_t)b * S * ld + h * 64;
  const unsigned short* Vh = Vb + (size_t)b * S * ld + h * 64;

  // Q fragments (A operand: m = lane&15, k = 8*(lane>>4)+j)
  bf16x8 qa0, qa1;
  {
    const unsigned short* qp = Qh + (size_t)(q0 + cc) * ld + g * 8;
    qa0 = __builtin_bit_cast(bf16x8, *(const u16x8*)qp);
    qa1 = __builtin_bit_cast(bf16x8, *(const u16x8*)(qp + 32));
  }

  bf16x8 ones8;
#pragma unroll
  for (int j = 0; j < 8; j++) ones8[j] = (__bf16)1.0f;

  // tr-read base addr (within-group lane m=cc): key_row = 8g + (m>>2),
  // chunk c8 = m&3; 16B-half swizzle s = g&1 (constant for keys 8g..8g+7)
  const unsigned vs_base = (unsigned)(uintptr_t)(void*)&Vs[0][0];
  const unsigned tr_a = vs_base + (unsigned)((8 * g + (cc >> 2)) * 32 +
                                             (((cc & 2) >> 1) ^ (g & 1)) * 16 +
                                             (cc & 1) * 8);

  f32x4 oacc[4];
#pragma unroll
  for (int i = 0; i < 4; i++) oacc[i] = (f32x4){0.f, 0.f, 0.f, 0.f};
  float Mx[4] = {-1e30f, -1e30f, -1e30f, -1e30f};
  float Lx[4] = {0.f, 0.f, 0.f, 0.f};
  char* PsW = (char*)&Ps[w][0];

  for (int kt = 0; kt < S / 64; ++kt) {
    __syncthreads();
    {  // stage K tile [64 keys][64 hd], XOR swizzled (unchanged)
      int r = t >> 3, c8 = (t & 7) * 8;
      const unsigned short* kp = Kh + (size_t)(kt * 64) * ld;
#pragma unroll
      for (int hh = 0; hh < 2; ++hh) {
        int row = r + hh * 32;
        u16x8 v = *(const u16x8*)(kp + (size_t)row * ld + c8);
        *(u16x8*)((char*)Ks + ((row * 128 + c8 * 2) ^ ((row & 7) << 4))) = v;
      }
      // stage V: tile bb = hd block; row-major [key][16hd], halves swizzled
      int key = t & 63, bb = t >> 6;
      const unsigned short* vp = Vh + (size_t)(kt * 64 + key) * ld + bb * 16;
      u16x8 v0 = *(const u16x8*)vp;
      u16x8 v1 = *(const u16x8*)(vp + 8);
      int sw = (key >> 3) & 1;
      char* vb = (char*)&Vs[bb][0] + key * 32;
      *(u16x8*)(vb + sw * 16) = v0;          // half0 -> pos 0^sw
      *(u16x8*)(vb + (1 - sw) * 16) = v1;    // half1 -> pos 1^sw
    }
    __syncthreads();

    // QK^T : 16 q-rows x 64 keys
    f32x4 sacc[4];
#pragma unroll
    for (int nb = 0; nb < 4; nb++) sacc[nb] = (f32x4){0.f, 0.f, 0.f, 0.f};
#pragma unroll
    for (int nb = 0; nb < 4; nb++) {
      int key = nb * 16 + cc;
      int rb = key * 128, xr = (key & 7) << 4;
      bf16x8 k0 = lds_frag(Ks, (rb + g * 16) ^ xr);
      bf16x8 k1 = lds_frag(Ks, (rb + 64 + g * 16) ^ xr);
      sacc[nb] = MFMA_BF16(qa0, k0, sacc[nb]);
      sacc[nb] = MFMA_BF16(qa1, k1, sacc[nb]);
    }

    // harmonic modification + row max
    float sm[4] = {-1e30f, -1e30f, -1e30f, -1e30f};
#pragma unroll
    for (int nb = 0; nb < 4; nb++)
#pragma unroll
      for (int r4 = 0; r4 < 4; r4++) {
        float sv = sacc[nb][r4] * 0.125f;          // / sqrt(64)
        sv += res * __sinf(sv + ph);
        sacc[nb][r4] = sv;
        sm[r4] = fmaxf(sm[r4], sv);
      }
#pragma unroll
    for (int d = 1; d < 16; d <<= 1)
#pragma unroll
      for (int r4 = 0; r4 < 4; r4++) sm[r4] = fmaxf(sm[r4], __shfl_xor(sm[r4], d, 16));

    float alpha[4];
#pragma unroll
    for (int r4 = 0; r4 < 4; r4++) {
      float nm = fmaxf(Mx[r4], sm[r4]);
      alpha[r4] = __expf(Mx[r4] - nm);
      Mx[r4] = nm;
    }
    // P = exp(s - M) -> bf16 into LDS (A-operand layout, XOR-swizzled rows)
#pragma unroll
    for (int nb = 0; nb < 4; nb++)
#pragma unroll
      for (int r4 = 0; r4 < 4; r4++) {
        float p = __expf(sacc[nb][r4] - Mx[r4]);
        int prow = g * 4 + r4, pcol = nb * 16 + cc;
        *(unsigned short*)(PsW + ((prow * 128 + pcol * 2) ^ ((prow & 7) << 4))) =
            f32_to_bf16(p);
      }

    // read P fragments (row = q = cc)
    bf16x8 pa0, pa1;
    {
      int xr = (cc & 7) << 4;
      pa0 = lds_frag((const unsigned short*)PsW, (cc * 128 + g * 16) ^ xr);
      pa1 = lds_frag((const unsigned short*)PsW, (cc * 128 + 64 + g * 16) ^ xr);
    }
    // psum via ones-MFMA: D[q][*] = row sums of P (all cols equal)
    f32x4 pacc = (f32x4){0.f, 0.f, 0.f, 0.f};
    pacc = MFMA_BF16(pa0, ones8, pacc);
    pacc = MFMA_BF16(pa1, ones8, pacc);
#pragma unroll
    for (int r4 = 0; r4 < 4; r4++) Lx[r4] = Lx[r4] * alpha[r4] + pacc[r4];
#pragma unroll
    for (int nb2 = 0; nb2 < 4; nb2++)
#pragma unroll
      for (int r4 = 0; r4 < 4; r4++) oacc[nb2][r4] *= alpha[r4];

    // PV: o += P(16x64) @ V(64x64); B-fragments via tr reads
    u32x2 trv[4][4];   // [hd_blk][lo0,lo1,hi0,hi1]
#pragma unroll
    for (int b2 = 0; b2 < 4; b2++) {
      unsigned a = tr_a + b2 * 2048;
      trv[b2][0] = tr_read(a);          // keys 8g+0..3
      trv[b2][1] = tr_read(a + 128);    // keys 8g+4..7
      trv[b2][2] = tr_read(a + 1024);   // keys 32+8g+0..3
      trv[b2][3] = tr_read(a + 1152);   // keys 32+8g+4..7
    }
    asm volatile("s_waitcnt lgkmcnt(0)" ::: "memory");
    __builtin_amdgcn_sched_barrier(0);
#pragma unroll
    for (int b2 = 0; b2 < 4; b2++) {
      bf16x8 v0 = __builtin_bit_cast(bf16x8,
          (u32x4){trv[b2][0][0], trv[b2][0][1], trv[b2][1][0], trv[b2][1][1]});
      bf16x8 v1 = __builtin_bit_cast(bf16x8,
          (u32x4){trv[b2][2][0], trv[b2][2][1], trv[b2][3][0], trv[b2][3][1]});
      oacc[b2] = MFMA_BF16(pa0, v0, oacc[b2]);
      oacc[b2] = MFMA_BF16(pa1, v1, oacc[b2]);
    }
  }

  // epilogue: normalize, write bf16 [B*S][ldo]
#pragma unroll
  for (int nb2 = 0; nb2 < 4; nb2++)
#pragma unroll
    for (int r4 = 0; r4 < 4; r4++) {
      float ov = oacc[nb2][r4] / Lx[r4];
      O[(size_t)(b * S + q0 + g * 4 + r4) * ldo + h * 64 + nb2 * 16 + cc] = f32_to_bf16(ov);
    }
}

// ---------------------------------------------------------------------------
// y = harmonic_ln(xin + radd): mean/std(ddof=1), std += stab*sin(pi*std)
// one block per row (D=1024). yf fp32 (required), yb bf16 (optional)
// ---------------------------------------------------------------------------
__global__ __launch_bounds__(256) void resid_harmonic_ln(const float* __restrict__ xin,
                                                         const float* __restrict__ radd,
                                                         const float* __restrict__ gamma,
                                                         const float* __restrict__ beta,
                                                         const float* __restrict__ stab,
                                                         float* __restrict__ yf,
                                                         unsigned short* __restrict__ yb) {
  const int row = blockIdx.x, t = threadIdx.x;
  const float* xr = xin + (size_t)row * 1024;
  const float* rr = radd + (size_t)row * 1024;
  float v[4], s = 0.f, ss = 0.f;
#pragma unroll
  for (int j = 0; j < 4; j++) {
    int idx = t + j * 256;
    v[j] = xr[idx] + rr[idx];
    s += v[j]; ss += v[j] * v[j];
  }
#pragma unroll
  for (int d = 1; d < 64; d <<= 1) { s += __shfl_xor(s, d); ss += __shfl_xor(ss, d); }
  __shared__ float sb[8];
  int lane = t & 63, wid = t >> 6;
  if (lane == 0) { sb[wid] = s; sb[4 + wid] = ss; }
  __syncthreads();
  s = sb[0] + sb[1] + sb[2] + sb[3];
  ss = sb[4] + sb[5] + sb[6] + sb[7];
  float mean = s * (1.f / 1024.f);
  float var = fmaxf((ss - 1024.f * mean * mean) * (1.f / 1023.f), 0.f);  // ddof=1
  float sd = sqrtf(var);
  sd += stab[0] * sinf(sd * 3.14159265358979323846f);
  float inv = 1.f / (sd + 1e-6f);
#pragma unroll
  for (int j = 0; j < 4; j++) {
    int idx = t + j * 256;
    float y = gamma[idx] * ((v[j] - mean) * inv) + beta[idx];
    yf[(size_t)row * 1024 + idx] = y;
    if (yb) yb[(size_t)row * 1024 + idx] = f32_to_bf16(y);
  }
}

// ---------------------------------------------------------------------------
extern "C" void kernel_launch(void* const* d_in, const int* in_sizes, int n_in,
                              void* d_out, int out_size, void* d_ws, size_t ws_size,
                              hipStream_t stream) {
  const float* x    = (const float*)d_in[0];
  const float* Wq   = (const float*)d_in[1];
  const float* bq   = (const float*)d_in[2];
  const float* Wk   = (const float*)d_in[3];
  const float* bk   = (const float*)d_in[4];
  const float* Wv   = (const float*)d_in[5];
  const float* bv   = (const float*)d_in[6];
  const float* Wo   = (const float*)d_in[7];
  const float* bo   = (const float*)d_in[8];
  const float* reso = (const float*)d_in[9];
  const float* phas = (const float*)d_in[10];
  const float* g1   = (const float*)d_in[11];
  const float* b1   = (const float*)d_in[12];
  const float* s1   = (const float*)d_in[13];
  const float* W1   = (const float*)d_in[14];
  const float* bf1  = (const float*)d_in[15];
  const float* W2   = (const float*)d_in[16];
  const float* bf2  = (const float*)d_in[17];
  const float* g2   = (const float*)d_in[18];
  const float* b2   = (const float*)d_in[19];
  const float* s2   = (const float*)d_in[20];

  const int BS = 4096;  // B*S

  // workspace layout (bytes); hb aliases qkv+xb (their lifetimes end first)
  char* ws = (char*)d_ws;
  const size_t OFF_QKV  = 0;                 // qkv bf16 [4096][3072]   25165824
  const size_t OFF_XB   = 25165824;          // xb bf16  [4096][1024]    8388608  (later: ao)
  const size_t OFF_WQKV = 33554432;          // Wqkv^T bf16 [3072][1024] 6291456
  const size_t OFF_WOT  = 39845888;          // Wo^T bf16 [1024][1024]   2097152
  const size_t OFF_W1T  = 41943040;          // W1^T bf16 [4096][1024]   8388608
  const size_t OFF_W2T  = 50331648;          // W2^T bf16 [1024][4096]   8388608
  const size_t OFF_BQKV = 58720256;          // bqkv f32 [3072]            12288
  const size_t OFF_T0   = 58736640;          // t0 f32 [4096][1024]     16777216
  const size_t OFF_X1   = 75513856;          // x1 f32 [4096][1024]     16777216
  const size_t OFF_X1B  = 92291072;          // x1b bf16 [4096][1024]    8388608
  // hb bf16 [4096][4096] = 33554432 @ offset 0 (over dead qkv+xb)

  unsigned short* qkv   = (unsigned short*)(ws + OFF_QKV);
  unsigned short* xb    = (unsigned short*)(ws + OFF_XB);
  unsigned short* ao    = (unsigned short*)(ws + OFF_XB);
  unsigned short* Wqkvt = (unsigned short*)(ws + OFF_WQKV);
  unsigned short* Wot   = (unsigned short*)(ws + OFF_WOT);
  unsigned short* W1t   = (unsigned short*)(ws + OFF_W1T);
  unsigned short* W2t   = (unsigned short*)(ws + OFF_W2T);
  float*          bqkv  = (float*)(ws + OFF_BQKV);
  float*          t0    = (float*)(ws + OFF_T0);
  float*          x1    = (float*)(ws + OFF_X1);
  unsigned short* x1b   = (unsigned short*)(ws + OFF_X1B);
  unsigned short* hb    = (unsigned short*)(ws + OFF_QKV);
  float*          out   = (float*)d_out;

  // 1. x -> bf16
  cvt_f32_bf16<<<4096, 256, 0, stream>>>(x, xb, BS * 1024);

  // 2. weight transposes (fp32 [K][N] -> bf16 [N][K])
  transpose_f32_bf16<<<dim3(32, 32), 256, 0, stream>>>(Wq, Wqkvt, 1024, 1024);
  transpose_f32_bf16<<<dim3(32, 32), 256, 0, stream>>>(Wk, Wqkvt + (size_t)1024 * 1024, 1024, 1024);
  transpose_f32_bf16<<<dim3(32, 32), 256, 0, stream>>>(Wv, Wqkvt + (size_t)2048 * 1024, 1024, 1024);
  transpose_f32_bf16<<<dim3(32, 32), 256, 0, stream>>>(Wo, Wot, 1024, 1024);
  transpose_f32_bf16<<<dim3(128, 32), 256, 0, stream>>>(W1, W1t, 1024, 4096);
  transpose_f32_bf16<<<dim3(32, 128), 256, 0, stream>>>(W2, W2t, 4096, 1024);

  // 3. pack qkv bias
  hipMemcpyAsync((void*)bqkv,          (const void*)bq, 1024 * 4, hipMemcpyDeviceToDevice, stream);
  hipMemcpyAsync((void*)(bqkv + 1024), (const void*)bk, 1024 * 4, hipMemcpyDeviceToDevice, stream);
  hipMemcpyAsync((void*)(bqkv + 2048), (const void*)bv, 1024 * 4, hipMemcpyDeviceToDevice, stream);

  // 4. fused QKV projection: [4096,1024] @ [1024,3072] -> bf16 qkv
  gemm_bt<128, 128, 0><<<dim3(24, 32), 256, 0, stream>>>(xb, Wqkvt, bqkv, qkv, nullptr,
                                                         4096, 3072, 1024);

  // 5. attention (reads q/k/v slices of packed qkv, ld=3072) -> ao bf16
  attn_fused<<<dim3(32, 32), 256, 0, stream>>>(qkv, qkv + 1024, qkv + 2048, 3072,
                                               reso, phas, ao, 1024);

  // 6. output projection -> t0 fp32
  gemm_bt<128, 64, 1><<<dim3(16, 32), 256, 0, stream>>>(ao, Wot, bo, nullptr, t0,
                                                        4096, 1024, 1024);

  // 7. x1 = harmonic_ln(x + attn_out)
  resid_harmonic_ln<<<4096, 256, 0, stream>>>(x, t0, g1, b1, s1, x1, x1b);

  // 8. FFN up + spectral activation -> hb bf16
  gemm_bt<128, 128, 2><<<dim3(32, 32), 256, 0, stream>>>(x1b, W1t, bf1, hb, nullptr,
                                                         4096, 4096, 1024);

  // 9. FFN down -> t0 fp32
  gemm_bt<128, 64, 1><<<dim3(16, 32), 256, 0, stream>>>(hb, W2t, bf2, nullptr, t0,
                                                        4096, 1024, 4096);

  // 10. out = harmonic_ln(x1 + ff)
  resid_harmonic_ln<<<4096, 256, 0, stream>>>(x1, t0, g2, b2, s2, out, nullptr);
}

// Round 5
// 488.676 us; speedup vs baseline: 1.0823x; 1.0738x over previous
//
#include <hip/hip_runtime.h>
#include <cstdint>
#include <cstddef>

// ---------------------------------------------------------------------------
// HarmonicTransformerLayer  B=2 S=2048 D=1024 H=16 HD=64 F=4096
// Round 5:
//   - GEMMs: 2-phase double-buffered LDS + prefetch-next-before-compute
//     (T3 minimum recipe). One barrier per K-step; global_load_lds width=16.
//   - attn: T14 async-stage split - K/V tile t+1 global loads issue right
//     after the stage barrier, consumed at top of t+1 (latency hidden under
//     QK/softmax/PV). Math identical to round 4.
// ---------------------------------------------------------------------------

typedef float  f32x4  __attribute__((ext_vector_type(4)));
typedef __bf16 bf16x8 __attribute__((ext_vector_type(8)));
typedef unsigned short u16x8 __attribute__((ext_vector_type(8)));
typedef unsigned short u16x4 __attribute__((ext_vector_type(4)));
typedef unsigned int   u32x2 __attribute__((ext_vector_type(2)));
typedef unsigned int   u32x4 __attribute__((ext_vector_type(4)));

#define MFMA_BF16(a, b, c) __builtin_amdgcn_mfma_f32_16x16x32_bf16((a), (b), (c), 0, 0, 0)

static __device__ __forceinline__ unsigned short f32_to_bf16(float f) {
  return __builtin_bit_cast(unsigned short, (__bf16)f);   // HW RNE cvt on gfx950
}
static __device__ __forceinline__ bf16x8 lds_frag(const unsigned short* base, int byte) {
  return __builtin_bit_cast(bf16x8, *(const u16x8*)((const char*)base + byte));
}
static __device__ __forceinline__ float spectral_act(float x) {
  const float c = 0.7978845608028654f;      // sqrt(2/pi)
  float g = 0.5f * x * (1.0f + tanhf(c * (x + 0.044715f * x * x * x)));
  return g + 0.5f * __sinf(x);              // ALPHA=0.5, BETA=1.0
}
static __device__ __forceinline__ void gload_lds16(const void* g, void* lds) {
  __builtin_amdgcn_global_load_lds((const __attribute__((address_space(1))) unsigned int*)g,
                                   (__attribute__((address_space(3))) unsigned int*)lds,
                                   16, 0, 0);
}
// ds_read_b64_tr_b16: per 16-lane group crossbar; lane i elem j =
// elem(i&3) of chunk supplied by lane 4j+(i>>2).
static __device__ __forceinline__ u32x2 tr_read(unsigned addr) {
  u32x2 r;
  asm volatile("ds_read_b64_tr_b16 %0, %1" : "=v"(r) : "v"(addr));
  return r;
}

// ---------------------------------------------------------------------------
// fp32 -> bf16 vector convert
// ---------------------------------------------------------------------------
__global__ __launch_bounds__(256) void cvt_f32_bf16(const float* __restrict__ in,
                                                    unsigned short* __restrict__ out, int n) {
  int i = (blockIdx.x * 256 + threadIdx.x) * 4;
  if (i < n) {
    float4 v = *(const float4*)(in + i);
    u16x4 o;
    o[0] = f32_to_bf16(v.x); o[1] = f32_to_bf16(v.y);
    o[2] = f32_to_bf16(v.z); o[3] = f32_to_bf16(v.w);
    *(u16x4*)(out + i) = o;
  }
}

// ---------------------------------------------------------------------------
// W [K][N] fp32  ->  Wt [N][K] bf16   (32x32 LDS tile transpose)
// ---------------------------------------------------------------------------
__global__ __launch_bounds__(256) void transpose_f32_bf16(const float* __restrict__ W,
                                                          unsigned short* __restrict__ Wt,
                                                          int K, int N) {
  __shared__ float tile[32][33];
  int tx = threadIdx.x & 31, ty = threadIdx.x >> 5;   // 32 x 8
  int k0 = blockIdx.y * 32, n0 = blockIdx.x * 32;
#pragma unroll
  for (int i = 0; i < 4; i++)
    tile[ty + i * 8][tx] = W[(size_t)(k0 + ty + i * 8) * N + n0 + tx];
  __syncthreads();
#pragma unroll
  for (int i = 0; i < 4; i++)
    Wt[(size_t)(n0 + ty + i * 8) * K + k0 + tx] = f32_to_bf16(tile[tx][ty + i * 8]);
}

// ---------------------------------------------------------------------------
// GEMM: C[M,N] = A[M,K](bf16) @ Bt[N,K]^T(bf16) + bias
// EPI 0: bf16 out, 1: fp32 out, 2: spectral(act) -> bf16 out
// 4 waves, wave tile (BM/2)x(BN/2), mfma 16x16x32.
// 2-phase: double-buffered LDS; issue stage(t+1) BEFORE compute(t); one
// __syncthreads per K-step (its vmcnt0 drain lands after compute cover).
// ---------------------------------------------------------------------------
template <int BM, int BN, int EPI>
__global__ __launch_bounds__(256) void gemm_bt(const unsigned short* __restrict__ A,
                                               const unsigned short* __restrict__ Bt,
                                               const float* __restrict__ bias,
                                               unsigned short* __restrict__ Cb,
                                               float* __restrict__ Cf,
                                               int M, int N, int K) {
  constexpr int MI = BM / 32;   // m-frags per wave
  constexpr int NI = BN / 32;   // n-frags per wave
  __shared__ unsigned short As[2][BM * 32];
  __shared__ unsigned short Bs[2][BN * 32];
  const int t = threadIdx.x;
  const int lane = t & 63, w = t >> 6;
  const int wr = w >> 1, wc = w & 1;
  const int g = lane >> 4, cc = lane & 15;
  const int row0 = blockIdx.y * BM, col0 = blockIdx.x * BN;

  f32x4 acc[MI][NI];
#pragma unroll
  for (int mi = 0; mi < MI; mi++)
#pragma unroll
    for (int ni = 0; ni < NI; ni++) acc[mi][ni] = (f32x4){0.f, 0.f, 0.f, 0.f};

  const int nk = K >> 5;
  // staging: lane -> row lane>>2 within the wave's 16 rows, chunk pre-swizzled
  const int srow = lane >> 2;
  const int schunk = (lane & 3) ^ (srow & 3);

  auto stage = [&](int buf, int kt) {
#pragma unroll
    for (int i = 0; i < BM / 64; ++i) {
      int r = i * 64 + w * 16;
      gload_lds16(A + (size_t)(row0 + r + srow) * K + (kt << 5) + schunk * 8,
                  &As[buf][r * 32]);
    }
#pragma unroll
    for (int i = 0; i < BN / 64; ++i) {
      int r = i * 64 + w * 16;
      gload_lds16(Bt + (size_t)(col0 + r + srow) * K + (kt << 5) + schunk * 8,
                  &Bs[buf][r * 32]);
    }
  };

  stage(0, 0);
  __syncthreads();               // vmcnt(0) drain: buf0 visible
  int cur = 0;
  for (int kt = 0; kt < nk; ++kt) {
    if (kt + 1 < nk) stage(cur ^ 1, kt + 1);   // issue next tile FIRST

    bf16x8 af[MI], bg[NI];
#pragma unroll
    for (int mi = 0; mi < MI; mi++) {
      int r = wr * (BM / 2) + mi * 16 + cc;
      af[mi] = lds_frag(&As[cur][0], r * 64 + ((g ^ (cc & 3)) << 4));
    }
#pragma unroll
    for (int ni = 0; ni < NI; ni++) {
      int r = wc * (BN / 2) + ni * 16 + cc;
      bg[ni] = lds_frag(&Bs[cur][0], r * 64 + ((g ^ (cc & 3)) << 4));
    }
#pragma unroll
    for (int mi = 0; mi < MI; mi++)
#pragma unroll
      for (int ni = 0; ni < NI; ni++)
        acc[mi][ni] = MFMA_BF16(af[mi], bg[ni], acc[mi][ni]);

    __syncthreads();             // stage(t+1) done + all reads of cur done
    cur ^= 1;
  }

#pragma unroll
  for (int mi = 0; mi < MI; mi++) {
#pragma unroll
    for (int ni = 0; ni < NI; ni++) {
      int col = col0 + wc * (BN / 2) + ni * 16 + cc;
      float bv = bias[col];
#pragma unroll
      for (int r4 = 0; r4 < 4; r4++) {
        int row = row0 + wr * (BM / 2) + mi * 16 + g * 4 + r4;
        float val = acc[mi][ni][r4] + bv;
        if (EPI == 2) val = spectral_act(val);
        if (EPI == 0 || EPI == 2) Cb[(size_t)row * N + col] = f32_to_bf16(val);
        else                      Cf[(size_t)row * N + col] = val;
      }
    }
  }
}

// ---------------------------------------------------------------------------
// Flash attention with harmonic score modification.
// grid (S/64, B*H); 4 waves, each wave owns 16 q-rows. 64-key tiles.
// scores s = (q.k)/8 ; s' = s + res*sin(s+ph) ; online softmax ; o = P@V
// T14 split: K/V tile t+1 global loads -> regs issued after the stage
// barrier; ds_write happens at top of t+1 (latency hidden under compute).
// ---------------------------------------------------------------------------
__global__ __launch_bounds__(256) void attn_fused(const unsigned short* __restrict__ Qb,
                                                  const unsigned short* __restrict__ Kb,
                                                  const unsigned short* __restrict__ Vb,
                                                  int ld,
                                                  const float* __restrict__ resonance,
                                                  const float* __restrict__ phase,
                                                  unsigned short* __restrict__ O, int ldo) {
  constexpr int S = 2048;
  __shared__ unsigned short Ks[64 * 64];     // [key][hd], XOR swizzled
  __shared__ unsigned short Vs[4][64 * 16];  // [hd_blk][key][hd%16], half-swizzled
  __shared__ unsigned short Ps[4][16 * 64];  // per-wave P staging

  const int t = threadIdx.x, lane = t & 63, w = t >> 6;
  const int g = lane >> 4, cc = lane & 15;
  const int bh = blockIdx.y, b = bh >> 4, h = bh & 15;
  const int q0 = blockIdx.x * 64 + w * 16;
  const float res = resonance[h], ph = phase[h];

  const unsigned short* Qh = Qb + (size_t)b * S * ld + h * 64;
  const unsigned short* Kh = Kb + (size_t)b * S * ld + h * 64;
  const unsigned short* Vh = Vb + (size_t)b * S * ld + h * 64;

  // Q fragments (A operand: m = lane&15, k = 8*(lane>>4)+j)
  bf16x8 qa0, qa1;
  {
    const unsigned short* qp = Qh + (size_t)(q0 + cc) * ld + g * 8;
    qa0 = __builtin_bit_cast(bf16x8, *(const u16x8*)qp);
    qa1 = __builtin_bit_cast(bf16x8, *(const u16x8*)(qp + 32));
  }

  bf16x8 ones8;
#pragma unroll
  for (int j = 0; j < 8; j++) ones8[j] = (__bf16)1.0f;

  // staging geometry
  const int krow = t >> 3, kc8 = (t & 7) * 8;      // K: 2 rows (krow, krow+32)
  const int vkey = t & 63, vb0 = (t >> 6) * 16;    // V: tile (t>>6), key row
  u16x8 kr0, kr1, vr0, vr1;                        // in-flight tile regs

  auto issue_loads = [&](int kt) {
    const unsigned short* kp = Kh + (size_t)(kt * 64) * ld;
    kr0 = *(const u16x8*)(kp + (size_t)krow * ld + kc8);
    kr1 = *(const u16x8*)(kp + (size_t)(krow + 32) * ld + kc8);
    const unsigned short* vp = Vh + (size_t)(kt * 64 + vkey) * ld + vb0;
    vr0 = *(const u16x8*)vp;
    vr1 = *(const u16x8*)(vp + 8);
  };
  auto stage_lds = [&]() {
    *(u16x8*)((char*)Ks + ((krow * 128 + kc8 * 2) ^ ((krow & 7) << 4))) = kr0;
    int row2 = krow + 32;
    *(u16x8*)((char*)Ks + ((row2 * 128 + kc8 * 2) ^ ((row2 & 7) << 4))) = kr1;
    int sw = (vkey >> 3) & 1;
    char* vb = (char*)&Vs[t >> 6][0] + vkey * 32;
    *(u16x8*)(vb + sw * 16) = vr0;          // half0 -> pos 0^sw
    *(u16x8*)(vb + (1 - sw) * 16) = vr1;    // half1 -> pos 1^sw
  };

  // tr-read base addr: key_row = 8g + (cc>>2), chunk = cc&3; half swizzle g&1
  const unsigned vs_base = (unsigned)(uintptr_t)(void*)&Vs[0][0];
  const unsigned tr_a = vs_base + (unsigned)((8 * g + (cc >> 2)) * 32 +
                                             (((cc & 2) >> 1) ^ (g & 1)) * 16 +
                                             (cc & 1) * 8);

  f32x4 oacc[4];
#pragma unroll
  for (int i = 0; i < 4; i++) oacc[i] = (f32x4){0.f, 0.f, 0.f, 0.f};
  float Mx[4] = {-1e30f, -1e30f, -1e30f, -1e30f};
  float Lx[4] = {0.f, 0.f, 0.f, 0.f};
  char* PsW = (char*)&Ps[w][0];

  issue_loads(0);
  for (int kt = 0; kt < S / 64; ++kt) {
    stage_lds();                  // waits on in-flight loads (compiler waitcnt)
    __syncthreads();              // K/V tile visible
    if (kt + 1 < S / 64) issue_loads(kt + 1);   // overlap with compute below

    // QK^T : 16 q-rows x 64 keys
    f32x4 sacc[4];
#pragma unroll
    for (int nb = 0; nb < 4; nb++) sacc[nb] = (f32x4){0.f, 0.f, 0.f, 0.f};
#pragma unroll
    for (int nb = 0; nb < 4; nb++) {
      int key = nb * 16 + cc;
      int rb = key * 128, xr = (key & 7) << 4;
      bf16x8 k0 = lds_frag(Ks, (rb + g * 16) ^ xr);
      bf16x8 k1 = lds_frag(Ks, (rb + 64 + g * 16) ^ xr);
      sacc[nb] = MFMA_BF16(qa0, k0, sacc[nb]);
      sacc[nb] = MFMA_BF16(qa1, k1, sacc[nb]);
    }

    // harmonic modification + row max
    float sm[4] = {-1e30f, -1e30f, -1e30f, -1e30f};
#pragma unroll
    for (int nb = 0; nb < 4; nb++)
#pragma unroll
      for (int r4 = 0; r4 < 4; r4++) {
        float sv = sacc[nb][r4] * 0.125f;          // / sqrt(64)
        sv += res * __sinf(sv + ph);
        sacc[nb][r4] = sv;
        sm[r4] = fmaxf(sm[r4], sv);
      }
#pragma unroll
    for (int d = 1; d < 16; d <<= 1)
#pragma unroll
      for (int r4 = 0; r4 < 4; r4++) sm[r4] = fmaxf(sm[r4], __shfl_xor(sm[r4], d, 16));

    float alpha[4];
#pragma unroll
    for (int r4 = 0; r4 < 4; r4++) {
      float nm = fmaxf(Mx[r4], sm[r4]);
      alpha[r4] = __expf(Mx[r4] - nm);
      Mx[r4] = nm;
    }
    // P = exp(s - M) -> bf16 into LDS (A-operand layout, XOR-swizzled rows)
#pragma unroll
    for (int nb = 0; nb < 4; nb++)
#pragma unroll
      for (int r4 = 0; r4 < 4; r4++) {
        float p = __expf(sacc[nb][r4] - Mx[r4]);
        int prow = g * 4 + r4, pcol = nb * 16 + cc;
        *(unsigned short*)(PsW + ((prow * 128 + pcol * 2) ^ ((prow & 7) << 4))) =
            f32_to_bf16(p);
      }

    // read P fragments (row = q = cc)
    bf16x8 pa0, pa1;
    {
      int xr = (cc & 7) << 4;
      pa0 = lds_frag((const unsigned short*)PsW, (cc * 128 + g * 16) ^ xr);
      pa1 = lds_frag((const unsigned short*)PsW, (cc * 128 + 64 + g * 16) ^ xr);
    }
    // psum via ones-MFMA: D[q][*] = row sums of P (all cols equal)
    f32x4 pacc = (f32x4){0.f, 0.f, 0.f, 0.f};
    pacc = MFMA_BF16(pa0, ones8, pacc);
    pacc = MFMA_BF16(pa1, ones8, pacc);
#pragma unroll
    for (int r4 = 0; r4 < 4; r4++) Lx[r4] = Lx[r4] * alpha[r4] + pacc[r4];
#pragma unroll
    for (int nb2 = 0; nb2 < 4; nb2++)
#pragma unroll
      for (int r4 = 0; r4 < 4; r4++) oacc[nb2][r4] *= alpha[r4];

    // PV: o += P(16x64) @ V(64x64); B-fragments via tr reads
    u32x2 trv[4][4];   // [hd_blk][lo0,lo1,hi0,hi1]
#pragma unroll
    for (int b2 = 0; b2 < 4; b2++) {
      unsigned a = tr_a + b2 * 2048;
      trv[b2][0] = tr_read(a);          // keys 8g+0..3
      trv[b2][1] = tr_read(a + 128);    // keys 8g+4..7
      trv[b2][2] = tr_read(a + 1024);   // keys 32+8g+0..3
      trv[b2][3] = tr_read(a + 1152);   // keys 32+8g+4..7
    }
    asm volatile("s_waitcnt lgkmcnt(0)" ::: "memory");
    __builtin_amdgcn_sched_barrier(0);
#pragma unroll
    for (int b2 = 0; b2 < 4; b2++) {
      bf16x8 v0 = __builtin_bit_cast(bf16x8,
          (u32x4){trv[b2][0][0], trv[b2][0][1], trv[b2][1][0], trv[b2][1][1]});
      bf16x8 v1 = __builtin_bit_cast(bf16x8,
          (u32x4){trv[b2][2][0], trv[b2][2][1], trv[b2][3][0], trv[b2][3][1]});
      oacc[b2] = MFMA_BF16(pa0, v0, oacc[b2]);
      oacc[b2] = MFMA_BF16(pa1, v1, oacc[b2]);
    }
    __syncthreads();                  // all reads done before next stage_lds
  }

  // epilogue: normalize, write bf16 [B*S][ldo]
#pragma unroll
  for (int nb2 = 0; nb2 < 4; nb2++)
#pragma unroll
    for (int r4 = 0; r4 < 4; r4++) {
      float ov = oacc[nb2][r4] / Lx[r4];
      O[(size_t)(b * S + q0 + g * 4 + r4) * ldo + h * 64 + nb2 * 16 + cc] = f32_to_bf16(ov);
    }
}

// ---------------------------------------------------------------------------
// y = harmonic_ln(xin + radd): mean/std(ddof=1), std += stab*sin(pi*std)
// one block per row (D=1024). yf fp32 (required), yb bf16 (optional)
// ---------------------------------------------------------------------------
__global__ __launch_bounds__(256) void resid_harmonic_ln(const float* __restrict__ xin,
                                                         const float* __restrict__ radd,
                                                         const float* __restrict__ gamma,
                                                         const float* __restrict__ beta,
                                                         const float* __restrict__ stab,
                                                         float* __restrict__ yf,
                                                         unsigned short* __restrict__ yb) {
  const int row = blockIdx.x, t = threadIdx.x;
  const float* xr = xin + (size_t)row * 1024;
  const float* rr = radd + (size_t)row * 1024;
  float v[4], s = 0.f, ss = 0.f;
#pragma unroll
  for (int j = 0; j < 4; j++) {
    int idx = t + j * 256;
    v[j] = xr[idx] + rr[idx];
    s += v[j]; ss += v[j] * v[j];
  }
#pragma unroll
  for (int d = 1; d < 64; d <<= 1) { s += __shfl_xor(s, d); ss += __shfl_xor(ss, d); }
  __shared__ float sb[8];
  int lane = t & 63, wid = t >> 6;
  if (lane == 0) { sb[wid] = s; sb[4 + wid] = ss; }
  __syncthreads();
  s = sb[0] + sb[1] + sb[2] + sb[3];
  ss = sb[4] + sb[5] + sb[6] + sb[7];
  float mean = s * (1.f / 1024.f);
  float var = fmaxf((ss - 1024.f * mean * mean) * (1.f / 1023.f), 0.f);  // ddof=1
  float sd = sqrtf(var);
  sd += stab[0] * sinf(sd * 3.14159265358979323846f);
  float inv = 1.f / (sd + 1e-6f);
#pragma unroll
  for (int j = 0; j < 4; j++) {
    int idx = t + j * 256;
    float y = gamma[idx] * ((v[j] - mean) * inv) + beta[idx];
    yf[(size_t)row * 1024 + idx] = y;
    if (yb) yb[(size_t)row * 1024 + idx] = f32_to_bf16(y);
  }
}

// ---------------------------------------------------------------------------
extern "C" void kernel_launch(void* const* d_in, const int* in_sizes, int n_in,
                              void* d_out, int out_size, void* d_ws, size_t ws_size,
                              hipStream_t stream) {
  const float* x    = (const float*)d_in[0];
  const float* Wq   = (const float*)d_in[1];
  const float* bq   = (const float*)d_in[2];
  const float* Wk   = (const float*)d_in[3];
  const float* bk   = (const float*)d_in[4];
  const float* Wv   = (const float*)d_in[5];
  const float* bv   = (const float*)d_in[6];
  const float* Wo   = (const float*)d_in[7];
  const float* bo   = (const float*)d_in[8];
  const float* reso = (const float*)d_in[9];
  const float* phas = (const float*)d_in[10];
  const float* g1   = (const float*)d_in[11];
  const float* b1   = (const float*)d_in[12];
  const float* s1   = (const float*)d_in[13];
  const float* W1   = (const float*)d_in[14];
  const float* bf1  = (const float*)d_in[15];
  const float* W2   = (const float*)d_in[16];
  const float* bf2  = (const float*)d_in[17];
  const float* g2   = (const float*)d_in[18];
  const float* b2   = (const float*)d_in[19];
  const float* s2   = (const float*)d_in[20];

  const int BS = 4096;  // B*S

  // workspace layout (bytes); hb aliases qkv+xb (their lifetimes end first)
  char* ws = (char*)d_ws;
  const size_t OFF_QKV  = 0;                 // qkv bf16 [4096][3072]   25165824
  const size_t OFF_XB   = 25165824;          // xb bf16  [4096][1024]    8388608  (later: ao)
  const size_t OFF_WQKV = 33554432;          // Wqkv^T bf16 [3072][1024] 6291456
  const size_t OFF_WOT  = 39845888;          // Wo^T bf16 [1024][1024]   2097152
  const size_t OFF_W1T  = 41943040;          // W1^T bf16 [4096][1024]   8388608
  const size_t OFF_W2T  = 50331648;          // W2^T bf16 [1024][4096]   8388608
  const size_t OFF_BQKV = 58720256;          // bqkv f32 [3072]            12288
  const size_t OFF_T0   = 58736640;          // t0 f32 [4096][1024]     16777216
  const size_t OFF_X1   = 75513856;          // x1 f32 [4096][1024]     16777216
  const size_t OFF_X1B  = 92291072;          // x1b bf16 [4096][1024]    8388608
  // hb bf16 [4096][4096] = 33554432 @ offset 0 (over dead qkv+xb)

  unsigned short* qkv   = (unsigned short*)(ws + OFF_QKV);
  unsigned short* xb    = (unsigned short*)(ws + OFF_XB);
  unsigned short* ao    = (unsigned short*)(ws + OFF_XB);
  unsigned short* Wqkvt = (unsigned short*)(ws + OFF_WQKV);
  unsigned short* Wot   = (unsigned short*)(ws + OFF_WOT);
  unsigned short* W1t   = (unsigned short*)(ws + OFF_W1T);
  unsigned short* W2t   = (unsigned short*)(ws + OFF_W2T);
  float*          bqkv  = (float*)(ws + OFF_BQKV);
  float*          t0    = (float*)(ws + OFF_T0);
  float*          x1    = (float*)(ws + OFF_X1);
  unsigned short* x1b   = (unsigned short*)(ws + OFF_X1B);
  unsigned short* hb    = (unsigned short*)(ws + OFF_QKV);
  float*          out   = (float*)d_out;

  // 1. x -> bf16
  cvt_f32_bf16<<<4096, 256, 0, stream>>>(x, xb, BS * 1024);

  // 2. weight transposes (fp32 [K][N] -> bf16 [N][K])
  transpose_f32_bf16<<<dim3(32, 32), 256, 0, stream>>>(Wq, Wqkvt, 1024, 1024);
  transpose_f32_bf16<<<dim3(32, 32), 256, 0, stream>>>(Wk, Wqkvt + (size_t)1024 * 1024, 1024, 1024);
  transpose_f32_bf16<<<dim3(32, 32), 256, 0, stream>>>(Wv, Wqkvt + (size_t)2048 * 1024, 1024, 1024);
  transpose_f32_bf16<<<dim3(32, 32), 256, 0, stream>>>(Wo, Wot, 1024, 1024);
  transpose_f32_bf16<<<dim3(128, 32), 256, 0, stream>>>(W1, W1t, 1024, 4096);
  transpose_f32_bf16<<<dim3(32, 128), 256, 0, stream>>>(W2, W2t, 4096, 1024);

  // 3. pack qkv bias
  hipMemcpyAsync((void*)bqkv,          (const void*)bq, 1024 * 4, hipMemcpyDeviceToDevice, stream);
  hipMemcpyAsync((void*)(bqkv + 1024), (const void*)bk, 1024 * 4, hipMemcpyDeviceToDevice, stream);
  hipMemcpyAsync((void*)(bqkv + 2048), (const void*)bv, 1024 * 4, hipMemcpyDeviceToDevice, stream);

  // 4. fused QKV projection: [4096,1024] @ [1024,3072] -> bf16 qkv
  gemm_bt<128, 128, 0><<<dim3(24, 32), 256, 0, stream>>>(xb, Wqkvt, bqkv, qkv, nullptr,
                                                         4096, 3072, 1024);

  // 5. attention (reads q/k/v slices of packed qkv, ld=3072) -> ao bf16
  attn_fused<<<dim3(32, 32), 256, 0, stream>>>(qkv, qkv + 1024, qkv + 2048, 3072,
                                               reso, phas, ao, 1024);

  // 6. output projection -> t0 fp32
  gemm_bt<128, 64, 1><<<dim3(16, 32), 256, 0, stream>>>(ao, Wot, bo, nullptr, t0,
                                                        4096, 1024, 1024);

  // 7. x1 = harmonic_ln(x + attn_out)
  resid_harmonic_ln<<<4096, 256, 0, stream>>>(x, t0, g1, b1, s1, x1, x1b);

  // 8. FFN up + spectral activation -> hb bf16
  gemm_bt<128, 128, 2><<<dim3(32, 32), 256, 0, stream>>>(x1b, W1t, bf1, hb, nullptr,
                                                         4096, 4096, 1024);

  // 9. FFN down -> t0 fp32
  gemm_bt<128, 64, 1><<<dim3(16, 32), 256, 0, stream>>>(hb, W2t, bf2, nullptr, t0,
                                                        4096, 1024, 4096);

  // 10. out = harmonic_ln(x1 + ff)
  resid_harmonic_ln<<<4096, 256, 0, stream>>>(x1, t0, g2, b2, s2, out, nullptr);
}